// Round 7
// baseline (647.996 us; speedup 1.0000x reference)
//
#include <hip/hip_runtime.h>
#include <cstdint>
#include <cstddef>

#define NB 8
#define NN 512
#define ND 256
#define NH 8
#define NM 8
#define NK 16
#define NR 8
#define NDH 32
#define BN (NB*NN)           // 4096 rows
#define BH (NB*NH)           // 64
#define BHN (BH*NN)          // 32768
#define BHM (BH*NM)          // 512
#define QOFF 16777216        // B*H*N*N

typedef __attribute__((ext_vector_type(8))) short bf16x8;
typedef __attribute__((ext_vector_type(8))) unsigned short u16x8;
typedef __attribute__((ext_vector_type(4))) float f32x4;

__device__ inline unsigned short f2bf(float x) {
  union { float f; unsigned u; } c; c.f = x;
  unsigned r = c.u + 0x7FFFu + ((c.u >> 16) & 1u);
  return (unsigned short)(r >> 16);
}
__device__ inline float bf2f(unsigned short x) {
  union { unsigned u; float f; } c; c.u = ((unsigned)x) << 16; return c.f;
}
__device__ inline float bflo(unsigned w2) {
  union { unsigned u; float f; } c; c.u = w2 << 16; return c.f;
}
__device__ inline float bfhi(unsigned w2) {
  union { unsigned u; float f; } c; c.u = w2 & 0xFFFF0000u; return c.f;
}

// ---------------- MLP: 64x64 tile, 4x4 per thread ----------------
__global__ __launch_bounds__(256) void k_mlp1(const float* __restrict__ xd, const float* __restrict__ xn,
                       const float* __restrict__ W1, const float* __restrict__ b1,
                       float* __restrict__ hid) {
  __shared__ float As[16][68];   // [k][i]
  __shared__ float Bs[16][68];   // [k][j]
  int t = threadIdx.x;
  int col0 = blockIdx.x * 64;
  int row0 = blockIdx.y * 64;
  int ar = t >> 2, ak = (t & 3) * 4;
  int bk = t >> 4, bc = (t & 15) * 4;
  int ty = t >> 4, tx = t & 15;
  float acc[4][4] = {};
  for (int k0 = 0; k0 < 2*ND; k0 += 16) {
    int gk = k0 + ak;
    const float* src = (gk < ND) ? (xd + (size_t)(row0+ar)*ND + gk)
                                 : (xn + (size_t)(row0+ar)*ND + (gk-ND));
    float4 av = *(const float4*)src;
    As[ak+0][ar] = av.x; As[ak+1][ar] = av.y; As[ak+2][ar] = av.z; As[ak+3][ar] = av.w;
    float4 bv = *(const float4*)(W1 + (size_t)(k0+bk)*ND + col0 + bc);
    *(float4*)&Bs[bk][bc] = bv;
    __syncthreads();
    #pragma unroll
    for (int kk = 0; kk < 16; kk++) {
      float4 a = *(const float4*)&As[kk][ty*4];
      float4 b = *(const float4*)&Bs[kk][tx*4];
      acc[0][0] += a.x*b.x; acc[0][1] += a.x*b.y; acc[0][2] += a.x*b.z; acc[0][3] += a.x*b.w;
      acc[1][0] += a.y*b.x; acc[1][1] += a.y*b.y; acc[1][2] += a.y*b.z; acc[1][3] += a.y*b.w;
      acc[2][0] += a.z*b.x; acc[2][1] += a.z*b.y; acc[2][2] += a.z*b.z; acc[2][3] += a.z*b.w;
      acc[3][0] += a.w*b.x; acc[3][1] += a.w*b.y; acc[3][2] += a.w*b.z; acc[3][3] += a.w*b.w;
    }
    __syncthreads();
  }
  float4 bb = *(const float4*)(b1 + col0 + tx*4);
  #pragma unroll
  for (int a = 0; a < 4; a++) {
    float4 o;
    o.x = fmaxf(acc[a][0] + bb.x, 0.f);
    o.y = fmaxf(acc[a][1] + bb.y, 0.f);
    o.z = fmaxf(acc[a][2] + bb.z, 0.f);
    o.w = fmaxf(acc[a][3] + bb.w, 0.f);
    *(float4*)(hid + (size_t)(row0+ty*4+a)*ND + col0 + tx*4) = o;
  }
}

__global__ __launch_bounds__(256) void k_mlp2(const float* __restrict__ hidp,
                       const float* __restrict__ W2, const float* __restrict__ b2,
                       float* __restrict__ z) {
  __shared__ float As[16][68];
  __shared__ float Bs[16][68];
  int t = threadIdx.x;
  int col0 = blockIdx.x * 64;
  int row0 = blockIdx.y * 64;
  int ar = t >> 2, ak = (t & 3) * 4;
  int bk = t >> 4, bc = (t & 15) * 4;
  int ty = t >> 4, tx = t & 15;
  float acc[4][4] = {};
  for (int k0 = 0; k0 < ND; k0 += 16) {
    float4 av = *(const float4*)(hidp + (size_t)(row0+ar)*ND + k0 + ak);
    As[ak+0][ar] = av.x; As[ak+1][ar] = av.y; As[ak+2][ar] = av.z; As[ak+3][ar] = av.w;
    float4 bv = *(const float4*)(W2 + (size_t)(k0+bk)*ND + col0 + bc);
    *(float4*)&Bs[bk][bc] = bv;
    __syncthreads();
    #pragma unroll
    for (int kk = 0; kk < 16; kk++) {
      float4 a = *(const float4*)&As[kk][ty*4];
      float4 b = *(const float4*)&Bs[kk][tx*4];
      acc[0][0] += a.x*b.x; acc[0][1] += a.x*b.y; acc[0][2] += a.x*b.z; acc[0][3] += a.x*b.w;
      acc[1][0] += a.y*b.x; acc[1][1] += a.y*b.y; acc[1][2] += a.y*b.z; acc[1][3] += a.y*b.w;
      acc[2][0] += a.z*b.x; acc[2][1] += a.z*b.y; acc[2][2] += a.z*b.z; acc[2][3] += a.z*b.w;
      acc[3][0] += a.w*b.x; acc[3][1] += a.w*b.y; acc[3][2] += a.w*b.z; acc[3][3] += a.w*b.w;
    }
    __syncthreads();
  }
  float4 bb = *(const float4*)(b2 + col0 + tx*4);
  #pragma unroll
  for (int a = 0; a < 4; a++) {
    float4 o;
    o.x = acc[a][0] + bb.x; o.y = acc[a][1] + bb.y;
    o.z = acc[a][2] + bb.z; o.w = acc[a][3] + bb.w;
    *(float4*)(z + (size_t)(row0+ty*4+a)*ND + col0 + tx*4) = o;
  }
}

// ---------------- zh normalize ----------------
__global__ void k_zhnorm(const float* __restrict__ z, float* __restrict__ zh) {
  int idx = blockIdx.x*256 + threadIdx.x;
  int d = idx & 31;
  int n = (idx >> 5) & (NN-1);
  int h = (idx >> 14) & (NH-1);
  int b = idx >> 17;
  float v = z[(size_t)(b*NN + n)*ND + h*NDH + d];
  float ss = v*v;
  #pragma unroll
  for (int m = 1; m < 32; m <<= 1) ss += __shfl_xor(ss, m);
  zh[idx] = v / fmaxf(sqrtf(ss), 1e-8f);
}

// ---------------- affinity + softmax -> P (bf16) ----------------
__global__ __launch_bounds__(256) void k_affinity(const float* __restrict__ zh, unsigned short* __restrict__ P) {
  int blk = blockIdx.x;               // 64 bh * 16 rowtiles
  int rt = blk & 15, bh = blk >> 4;
  int r0 = rt*32;
  const float* base = zh + (size_t)bh*NN*NDH;
  __shared__ float qs[32][33];
  __shared__ float ks[32][36];        // [d][s]
  int t = threadIdx.x;
  int sr = t >> 3, dq = (t & 7)*4;
  {
    float4 v = *(const float4*)(base + (size_t)(r0+sr)*NDH + dq);
    qs[sr][dq] = v.x; qs[sr][dq+1] = v.y; qs[sr][dq+2] = v.z; qs[sr][dq+3] = v.w;
  }
  int cr = t >> 3;
  int cq = t & 7;
  float acc[16][4];
  #pragma unroll
  for (int ti = 0; ti < 16; ti++) { acc[ti][0]=0; acc[ti][1]=0; acc[ti][2]=0; acc[ti][3]=0; }
  for (int ti = 0; ti < 16; ti++) {
    int s0 = ti*32;
    __syncthreads();
    {
      float4 v = *(const float4*)(base + (size_t)(s0+sr)*NDH + dq);
      ks[dq+0][sr] = v.x; ks[dq+1][sr] = v.y; ks[dq+2][sr] = v.z; ks[dq+3][sr] = v.w;
    }
    __syncthreads();
    #pragma unroll
    for (int d = 0; d < 32; d++) {
      float qv = qs[cr][d];
      float4 kv = *(const float4*)&ks[d][cq*4];
      acc[ti][0] += qv*kv.x; acc[ti][1] += qv*kv.y;
      acc[ti][2] += qv*kv.z; acc[ti][3] += qv*kv.w;
    }
  }
  int gr = r0 + cr;
  float mx = -1e30f;
  #pragma unroll
  for (int ti = 0; ti < 16; ti++) {
    #pragma unroll
    for (int j = 0; j < 4; j++) {
      int s = ti*32 + cq*4 + j;
      float v = (s == gr) ? -1e9f : acc[ti][j]*0.0625f;
      acc[ti][j] = v;
      mx = fmaxf(mx, v);
    }
  }
  mx = fmaxf(mx, __shfl_xor(mx, 1));
  mx = fmaxf(mx, __shfl_xor(mx, 2));
  mx = fmaxf(mx, __shfl_xor(mx, 4));
  float sum = 0.f;
  #pragma unroll
  for (int ti = 0; ti < 16; ti++) {
    #pragma unroll
    for (int j = 0; j < 4; j++) { float e = expf(acc[ti][j]-mx); acc[ti][j] = e; sum += e; }
  }
  sum += __shfl_xor(sum,1); sum += __shfl_xor(sum,2); sum += __shfl_xor(sum,4);
  float inv = 1.f/sum;
  unsigned short* prow = P + ((size_t)(bh*NN) + gr)*NN;
  #pragma unroll
  for (int ti = 0; ti < 16; ti++) {
    uint2 pk;
    pk.x = (unsigned)f2bf(acc[ti][0]*inv) | ((unsigned)f2bf(acc[ti][1]*inv) << 16);
    pk.y = (unsigned)f2bf(acc[ti][2]*inv) | ((unsigned)f2bf(acc[ti][3]*inv) << 16);
    *(uint2*)(prow + ti*32 + cq*4) = pk;
  }
}

// ---------------- DP: symmetrize + row-normalize -> DP,DPsq (bf16) + rowsum/rowsq ----------------
__global__ __launch_bounds__(256) void k_dp(const unsigned short* __restrict__ P,
                       unsigned short* __restrict__ DPo, unsigned short* __restrict__ DPq,
                       float* __restrict__ rs, float* __restrict__ rq) {
  int blk = blockIdx.x;               // 64*16
  int rt = blk & 15, bh = blk >> 4;
  int r0 = rt*32;
  const unsigned short* Pb = P + (size_t)bh*NN*NN;
  __shared__ float Bs[32][33];
  int t = threadIdx.x;
  int r = t >> 3, q4 = (t & 7)*4;
  float pn[16][4];
  float rowacc = 0.f;
  for (int ti = 0; ti < 16; ti++) {
    int s0 = ti*32;
    __syncthreads();
    {
      uint2 v = *(const uint2*)(Pb + (size_t)(s0+r)*NN + r0 + q4);
      Bs[r][q4+0] = bf2f((unsigned short)(v.x & 0xFFFF));
      Bs[r][q4+1] = bf2f((unsigned short)(v.x >> 16));
      Bs[r][q4+2] = bf2f((unsigned short)(v.y & 0xFFFF));
      Bs[r][q4+3] = bf2f((unsigned short)(v.y >> 16));
    }
    uint2 av = *(const uint2*)(Pb + (size_t)(r0+r)*NN + s0 + q4);
    __syncthreads();
    float a0 = bf2f((unsigned short)(av.x & 0xFFFF));
    float a1 = bf2f((unsigned short)(av.x >> 16));
    float a2 = bf2f((unsigned short)(av.y & 0xFFFF));
    float a3 = bf2f((unsigned short)(av.y >> 16));
    float p0 = fmaxf(0.5f*(a0 + Bs[q4+0][r]), 1e-8f);
    float p1 = fmaxf(0.5f*(a1 + Bs[q4+1][r]), 1e-8f);
    float p2 = fmaxf(0.5f*(a2 + Bs[q4+2][r]), 1e-8f);
    float p3 = fmaxf(0.5f*(a3 + Bs[q4+3][r]), 1e-8f);
    pn[ti][0]=p0; pn[ti][1]=p1; pn[ti][2]=p2; pn[ti][3]=p3;
    rowacc += p0+p1+p2+p3;
  }
  rowacc += __shfl_xor(rowacc,1); rowacc += __shfl_xor(rowacc,2); rowacc += __shfl_xor(rowacc,4);
  float inv = 1.f / fmaxf(rowacc, 1e-8f);
  unsigned short* drow = DPo + ((size_t)(bh*NN) + r0 + r)*NN;
  unsigned short* qrow = DPq + ((size_t)(bh*NN) + r0 + r)*NN;
  float rsv = 0.f, rqv = 0.f;
  #pragma unroll
  for (int ti = 0; ti < 16; ti++) {
    float o0 = fmaxf(1.f - pn[ti][0]*inv, 0.f);
    float o1 = fmaxf(1.f - pn[ti][1]*inv, 0.f);
    float o2 = fmaxf(1.f - pn[ti][2]*inv, 0.f);
    float o3 = fmaxf(1.f - pn[ti][3]*inv, 0.f);
    rsv += o0+o1+o2+o3;
    rqv += o0*o0 + o1*o1 + o2*o2 + o3*o3;
    uint2 pk;
    pk.x = (unsigned)f2bf(o0) | ((unsigned)f2bf(o1) << 16);
    pk.y = (unsigned)f2bf(o2) | ((unsigned)f2bf(o3) << 16);
    *(uint2*)(drow + ti*32 + q4) = pk;
    uint2 qk;
    qk.x = (unsigned)f2bf(o0*o0) | ((unsigned)f2bf(o1*o1) << 16);
    qk.y = (unsigned)f2bf(o2*o2) | ((unsigned)f2bf(o3*o3) << 16);
    *(uint2*)(qrow + ti*32 + q4) = qk;
  }
  rsv += __shfl_xor(rsv,1); rsv += __shfl_xor(rsv,2); rsv += __shfl_xor(rsv,4);
  rqv += __shfl_xor(rqv,1); rqv += __shfl_xor(rqv,2); rqv += __shfl_xor(rqv,4);
  if ((t & 7) == 0) {
    rs[bh*NN + r0 + r] = rsv;
    rq[bh*NN + r0 + r] = rqv;
  }
}

// ---------------- slot graphs: G, g_reg, DG ----------------
__global__ void k_slots(const float* __restrict__ Up, float* __restrict__ G,
                        float* __restrict__ DG, float* __restrict__ greg) {
  __shared__ float U[NM*NK*NR];
  __shared__ float Gs[NM*NK*NK];
  __shared__ float rsx[NM*NK];
  __shared__ float vn[NM];
  __shared__ float gram[NM*NM];
  int t = threadIdx.x;
  for (int i = t; i < NM*NK*NR; i += 256) {
    float x = Up[i];
    U[i] = fmaxf(x, 0.f) + log1pf(expf(-fabsf(x)));
  }
  __syncthreads();
  for (int i = t; i < NM*NK*NK; i += 256) {
    int m = i >> 8, k = (i >> 4) & 15, j = i & 15;
    float acc = 0.f;
    #pragma unroll
    for (int r = 0; r < NR; r++) acc += U[(m*NK+k)*NR + r]*U[(m*NK+j)*NR + r];
    Gs[i] = acc;
  }
  __syncthreads();
  for (int i = t; i < NM*NK; i += 256) {
    float s = 0.f;
    #pragma unroll
    for (int j = 0; j < NK; j++) s += Gs[i*NK + j];
    rsx[i] = fmaxf(s, 1e-8f);
  }
  __syncthreads();
  for (int i = t; i < NM*NK*NK; i += 256) { Gs[i] /= rsx[i >> 4]; G[i] = Gs[i]; }
  __syncthreads();
  for (int i = t; i < NM; i += 256) {
    float s = 0.f;
    for (int j = 0; j < NK*NK; j++) { float g = Gs[i*NK*NK + j]; s += g*g; }
    vn[i] = fmaxf(sqrtf(s), 1e-8f);
  }
  __syncthreads();
  for (int i = t; i < NM*NM; i += 256) {
    int a = i >> 3, b = i & 7;
    float s = 0.f;
    for (int j = 0; j < NK*NK; j++) s += Gs[a*NK*NK + j]*Gs[b*NK*NK + j];
    gram[i] = s / (vn[a]*vn[b]);
  }
  __syncthreads();
  if (t == 0) {
    float s = 0.f;
    for (int i = 0; i < NM*NM; i++) if ((i >> 3) != (i & 7)) s += gram[i];
    greg[0] = 0.1f * s / (float)(NM*(NM-1));
  }
  for (int i = t; i < NM*NK*NK; i += 256) {
    int m = i >> 8, k = (i >> 4) & 15, j = i & 15;
    float dk = fmaxf(Gs[m*NK*NK + k*NK + k], 1e-8f);
    float dj = fmaxf(Gs[m*NK*NK + j*NK + j], 1e-8f);
    float den = fmaxf(sqrtf(dk*dj), 1e-8f);
    float c = fminf(fmaxf(Gs[i]/den, -1.f), 1.f);
    float d = fmaxf(1.f - c, 0.f);
    if (k == j) d = 0.f;
    DG[i] = d;
  }
}

// ---------------- fused GW: LDS-staged MFMA streams, bank-exact slot swizzle ----------------
#define DSTR 40     // DP tile row = 80 B = 5 x 16B slots
#define KST 522     // KT row stride (u16): bf16 K matrix [16][512]
#define PSTR 520    // PiT row stride (u16)
// SLOT[r&3][c]: 16B-slot of column-group c in row r. Verified 2-way banks on
// both ds_write_b128 staging and ds_read_b128 MFMA fragments (quarter-wave).
__device__ __constant__ int SLOT_LUT[4][4] = {{1,2,3,4},{1,3,0,2},{2,3,4,0},{0,4,1,2}};
__global__ __launch_bounds__(512, 2) void k_gw(
    const unsigned short* __restrict__ DPb,   // [64][512][512] bf16
    const unsigned short* __restrict__ DPq,   // DP^2
    const float* __restrict__ rs, const float* __restrict__ rq,
    const float* __restrict__ Gm, const float* __restrict__ DGm,
    unsigned short* __restrict__ PiGs, unsigned short* __restrict__ Pis,
    float* __restrict__ gwv) {
  int blk = blockIdx.x;
  int xcd = blk & 7, seq = blk >> 3;
  int bh = xcd*8 + (seq >> 3);                // 8 m of one bh share an XCD's L2
  int m  = seq & 7;
  __shared__ __align__(16) unsigned short DPs[512*DSTR];   // 40.96 KB
  __shared__ __align__(16) unsigned short KT[16*KST];      // 16.7 KB
  __shared__ __align__(16) unsigned short PiT[16*PSTR];    // 16.6 KB
  __shared__ __align__(16) float u[512];
  __shared__ __align__(16) float vv[16];
  __shared__ float ml[16], t2s[16], dgrow[16];
  __shared__ float Gsm[16][17], DGsm[16][17];
  __shared__ float sred[8][16];
  int t = threadIdx.x;
  int lane = t & 63, w = t >> 6;
  int il = lane & 15, q = lane >> 4;
  int g = t >> 4, kc = t & 15;
  if (t < 256) { Gsm[t>>4][t&15] = Gm[m*256 + t]; DGsm[t>>4][t&15] = DGm[m*256 + t]; }
  __syncthreads();
  if (t < 16) {
    float s = 0.f;
    #pragma unroll
    for (int l = 0; l < 16; l++) s += DGsm[t][l];
    dgrow[t] = s;
  }
  const unsigned short* DPbase = DPb + (size_t)bh*NN*NN;
  const unsigned short* DQbase = DPq + (size_t)bh*NN*NN;
  float rsv = rs[bh*NN + t]*(1.f/8192.f);
  float rqv = rq[bh*NN + t]*(1.f/512.f);
  float Kt[16];
  float creg[4][4];
  float ut = 0.f;
  int r0i = t >> 2, ci = (t & 3)*8;
  // per-thread constant swizzled offsets
  int wslot = SLOT_LUT[r0i & 3][t & 3];               // staging write slot
  int rslot = SLOT_LUT[il & 3][q];                    // MFMA read slot
  int woff = r0i*DSTR + wslot*8;
  int roff0 = (w*64 + il)*DSTR + rslot*8;
  for (int itr = 0; itr < 3; ++itr) {
    if (t < 16) {
      float s = 0.f;
      #pragma unroll
      for (int l = 0; l < 16; l++) { float d = DGsm[t][l]; s += d*d*((itr == 0) ? (1.f/16.f) : ml[l]); }
      t2s[t] = s;
    }
    __syncthreads();
    if (itr == 0) {
      // closed form: W uniform -> cross = rsv*dgrow, t1 = rqv
      #pragma unroll
      for (int k = 0; k < 16; k++) {
        float c = fmaxf(rqv + t2s[k] - 2.f*rsv*dgrow[k], 0.f);
        float e = fmaxf(__expf(-20.f*c), 1e-12f);
        Kt[k] = e;
        KT[k*KST + t] = f2bf(e);
      }
    } else {
      f32x4 aW0={0,0,0,0}, aW1={0,0,0,0}, aW2={0,0,0,0}, aW3={0,0,0,0};
      f32x4 aV0={0,0,0,0}, aV1={0,0,0,0}, aV2={0,0,0,0}, aV3={0,0,0,0};
      float4 c0, c1, c2, c3;
      c0 = *(const float4*)(DPbase + (size_t)r0i*NN + ci);
      c1 = *(const float4*)(DPbase + (size_t)(r0i+128)*NN + ci);
      c2 = *(const float4*)(DPbase + (size_t)(r0i+256)*NN + ci);
      c3 = *(const float4*)(DPbase + (size_t)(r0i+384)*NN + ci);
      // W sweep over DP
      for (int p = 0; p < 16; p++) {
        *(float4*)&DPs[woff] = c0;
        *(float4*)&DPs[woff + 128*DSTR] = c1;
        *(float4*)&DPs[woff + 256*DSTR] = c2;
        *(float4*)&DPs[woff + 384*DSTR] = c3;
        __syncthreads();
        {
          const unsigned short* src = (p < 15) ? (DPbase + (p+1)*32) : DQbase;
          c0 = *(const float4*)(src + (size_t)r0i*NN + ci);
          c1 = *(const float4*)(src + (size_t)(r0i+128)*NN + ci);
          c2 = *(const float4*)(src + (size_t)(r0i+256)*NN + ci);
          c3 = *(const float4*)(src + (size_t)(r0i+384)*NN + ci);
        }
        bf16x8 af = *(const bf16x8*)&PiT[il*PSTR + p*32 + q*8];
        bf16x8 b0 = *(const bf16x8*)&DPs[roff0];
        bf16x8 b1 = *(const bf16x8*)&DPs[roff0 + 16*DSTR];
        bf16x8 b2 = *(const bf16x8*)&DPs[roff0 + 32*DSTR];
        bf16x8 b3 = *(const bf16x8*)&DPs[roff0 + 48*DSTR];
        aW0 = __builtin_amdgcn_mfma_f32_16x16x32_bf16(af, b0, aW0, 0, 0, 0);
        aW1 = __builtin_amdgcn_mfma_f32_16x16x32_bf16(af, b1, aW1, 0, 0, 0);
        aW2 = __builtin_amdgcn_mfma_f32_16x16x32_bf16(af, b2, aW2, 0, 0, 0);
        aW3 = __builtin_amdgcn_mfma_f32_16x16x32_bf16(af, b3, aW3, 0, 0, 0);
        __syncthreads();
      }
      // V sweep over DPsq
      for (int p = 0; p < 16; p++) {
        *(float4*)&DPs[woff] = c0;
        *(float4*)&DPs[woff + 128*DSTR] = c1;
        *(float4*)&DPs[woff + 256*DSTR] = c2;
        *(float4*)&DPs[woff + 384*DSTR] = c3;
        __syncthreads();
        if (p < 15) {
          const unsigned short* src = DQbase + (p+1)*32;
          c0 = *(const float4*)(src + (size_t)r0i*NN + ci);
          c1 = *(const float4*)(src + (size_t)(r0i+128)*NN + ci);
          c2 = *(const float4*)(src + (size_t)(r0i+256)*NN + ci);
          c3 = *(const float4*)(src + (size_t)(r0i+384)*NN + ci);
        }
        bf16x8 af = *(const bf16x8*)&PiT[il*PSTR + p*32 + q*8];
        bf16x8 b0 = *(const bf16x8*)&DPs[roff0];
        bf16x8 b1 = *(const bf16x8*)&DPs[roff0 + 16*DSTR];
        bf16x8 b2 = *(const bf16x8*)&DPs[roff0 + 32*DSTR];
        bf16x8 b3 = *(const bf16x8*)&DPs[roff0 + 48*DSTR];
        aV0 = __builtin_amdgcn_mfma_f32_16x16x32_bf16(af, b0, aV0, 0, 0, 0);
        aV1 = __builtin_amdgcn_mfma_f32_16x16x32_bf16(af, b1, aV1, 0, 0, 0);
        aV2 = __builtin_amdgcn_mfma_f32_16x16x32_bf16(af, b2, aV2, 0, 0, 0);
        aV3 = __builtin_amdgcn_mfma_f32_16x16x32_bf16(af, b3, aV3, 0, 0, 0);
        __syncthreads();
      }
      // epilogue: t1 = rowsum(V) over k; cross = W x DG; C -> KT(bf16)
      #pragma unroll
      for (int tt = 0; tt < 4; tt++) {
        f32x4 av = (tt==0)?aW0:((tt==1)?aW1:((tt==2)?aW2:aW3));
        f32x4 bv = (tt==0)?aV0:((tt==1)?aV1:((tt==2)?aV2:aV3));
        float tv = bv[0]+bv[1]+bv[2]+bv[3];
        tv += __shfl_xor(tv, 16); tv += __shfl_xor(tv, 32);
        float pc[16];
        #pragma unroll
        for (int k = 0; k < 16; k++) {
          pc[k] = av[0]*DGsm[k][q*4+0] + av[1]*DGsm[k][q*4+1]
                + av[2]*DGsm[k][q*4+2] + av[3]*DGsm[k][q*4+3];
        }
        #pragma unroll
        for (int k = 0; k < 16; k++) { pc[k] += __shfl_xor(pc[k], 16); pc[k] += __shfl_xor(pc[k], 32); }
        int i = w*64 + tt*16 + il;
        #pragma unroll
        for (int kk = 0; kk < 4; kk++) {
          int k = q*4 + kk;
          float c = fmaxf(tv + t2s[k] - 2.f*pc[k], 0.f);
          creg[tt][kk] = c;
          KT[k*KST + i] = f2bf(fmaxf(__expf(-20.f*c), 1e-12f));
        }
      }
      __syncthreads();
      // cache own K column in registers
      #pragma unroll
      for (int k = 0; k < 16; k++) Kt[k] = bf2f(KT[k*KST + t]);
    }
    __syncthreads();
    // ---- sinkhorn: 10 iters; u-update register-only, v-update vectorized ----
    if (t < 16) vv[t] = 1.f/16.f;
    __syncthreads();
    for (int si = 0; si < 10; si++) {
      float4 va = *(const float4*)&vv[0];
      float4 vb = *(const float4*)&vv[4];
      float4 vc = *(const float4*)&vv[8];
      float4 vd = *(const float4*)&vv[12];
      float s = Kt[0]*va.x + Kt[1]*va.y + Kt[2]*va.z + Kt[3]*va.w
              + Kt[4]*vb.x + Kt[5]*vb.y + Kt[6]*vb.z + Kt[7]*vb.w
              + Kt[8]*vc.x + Kt[9]*vc.y + Kt[10]*vc.z + Kt[11]*vc.w
              + Kt[12]*vd.x + Kt[13]*vd.y + Kt[14]*vd.z + Kt[15]*vd.w;
      ut = (1.f/512.f)/(s + 1e-6f);
      u[t] = ut;
      __syncthreads();
      const unsigned* kp = (const unsigned*)&KT[kc*KST + g*16];
      unsigned k0 = kp[0], k1 = kp[1], k2 = kp[2], k3 = kp[3];
      unsigned k4 = kp[4], k5 = kp[5], k6 = kp[6], k7 = kp[7];
      float4 ua = *(const float4*)&u[g*16];
      float4 ub = *(const float4*)&u[g*16+4];
      float4 uc = *(const float4*)&u[g*16+8];
      float4 ud = *(const float4*)&u[g*16+12];
      float p = bflo(k0)*ua.x + bfhi(k0)*ua.y + bflo(k1)*ua.z + bfhi(k1)*ua.w
              + bflo(k2)*ub.x + bfhi(k2)*ub.y + bflo(k3)*ub.z + bfhi(k3)*ub.w
              + bflo(k4)*uc.x + bfhi(k4)*uc.y + bflo(k5)*uc.z + bfhi(k5)*uc.w
              + bflo(k6)*ud.x + bfhi(k6)*ud.y + bflo(k7)*ud.z + bfhi(k7)*ud.w;
      p += __shfl_xor(p, 16); p += __shfl_xor(p, 32);
      if (lane < 16) sred[w][lane] = p;
      __syncthreads();
      if (t < 16) {
        float S = sred[0][t]+sred[1][t]+sred[2][t]+sred[3][t]
                + sred[4][t]+sred[5][t]+sred[6][t]+sred[7][t];
        float nv = (1.f/16.f)/(S + 1e-6f);
        vv[t] = nv;
        ml[t] = nv*S;        // massl, valid at si==9
      }
      __syncthreads();
    }
    if (itr < 2) {
      // rebuild PiT (bf16) for next iter's MFMA streams
      const unsigned* kp = (const unsigned*)&KT[kc*KST + g*16];
      float4 ua = *(const float4*)&u[g*16];
      float4 ub = *(const float4*)&u[g*16+4];
      float4 uc = *(const float4*)&u[g*16+8];
      float4 ud = *(const float4*)&u[g*16+12];
      float vk = vv[kc];
      unsigned* pp = (unsigned*)&PiT[kc*PSTR + g*16];
      unsigned kx;
      kx = kp[0]; pp[0] = (unsigned)f2bf(ua.x*bflo(kx)*vk) | ((unsigned)f2bf(ua.y*bfhi(kx)*vk) << 16);
      kx = kp[1]; pp[1] = (unsigned)f2bf(ua.z*bflo(kx)*vk) | ((unsigned)f2bf(ua.w*bfhi(kx)*vk) << 16);
      kx = kp[2]; pp[2] = (unsigned)f2bf(ub.x*bflo(kx)*vk) | ((unsigned)f2bf(ub.y*bfhi(kx)*vk) << 16);
      kx = kp[3]; pp[3] = (unsigned)f2bf(ub.z*bflo(kx)*vk) | ((unsigned)f2bf(ub.w*bfhi(kx)*vk) << 16);
      kx = kp[4]; pp[4] = (unsigned)f2bf(uc.x*bflo(kx)*vk) | ((unsigned)f2bf(uc.y*bfhi(kx)*vk) << 16);
      kx = kp[5]; pp[5] = (unsigned)f2bf(uc.z*bflo(kx)*vk) | ((unsigned)f2bf(uc.w*bfhi(kx)*vk) << 16);
      kx = kp[6]; pp[6] = (unsigned)f2bf(ud.x*bflo(kx)*vk) | ((unsigned)f2bf(ud.y*bfhi(kx)*vk) << 16);
      kx = kp[7]; pp[7] = (unsigned)f2bf(ud.z*bflo(kx)*vk) | ((unsigned)f2bf(ud.w*bfhi(kx)*vk) << 16);
      __syncthreads();
    } else {
      // ---- final: Pi/PiG stacks + gw ----
      float4 va = *(const float4*)&vv[0];
      float4 vb = *(const float4*)&vv[4];
      float4 vc = *(const float4*)&vv[8];
      float4 vd = *(const float4*)&vv[12];
      float vr[16] = {va.x,va.y,va.z,va.w, vb.x,vb.y,vb.z,vb.w,
                      vc.x,vc.y,vc.z,vc.w, vd.x,vd.y,vd.z,vd.w};
      float pi[16];
      #pragma unroll
      for (int k = 0; k < 16; k++) pi[k] = ut*Kt[k]*vr[k];
      size_t ob = ((size_t)bh*NN + t)*128 + m*16;
      {
        uint4 w0, w1;
        w0.x = (unsigned)f2bf(pi[0])  | ((unsigned)f2bf(pi[1])  << 16);
        w0.y = (unsigned)f2bf(pi[2])  | ((unsigned)f2bf(pi[3])  << 16);
        w0.z = (unsigned)f2bf(pi[4])  | ((unsigned)f2bf(pi[5])  << 16);
        w0.w = (unsigned)f2bf(pi[6])  | ((unsigned)f2bf(pi[7])  << 16);
        w1.x = (unsigned)f2bf(pi[8])  | ((unsigned)f2bf(pi[9])  << 16);
        w1.y = (unsigned)f2bf(pi[10]) | ((unsigned)f2bf(pi[11]) << 16);
        w1.z = (unsigned)f2bf(pi[12]) | ((unsigned)f2bf(pi[13]) << 16);
        w1.w = (unsigned)f2bf(pi[14]) | ((unsigned)f2bf(pi[15]) << 16);
        *(uint4*)(Pis + ob) = w0;
        *(uint4*)(Pis + ob + 8) = w1;
      }
      float pig[16];
      #pragma unroll
      for (int l = 0; l < 16; l++) {
        float s = 0.f;
        #pragma unroll
        for (int k = 0; k < 16; k++) s += pi[k]*Gsm[k][l];
        pig[l] = s;
      }
      {
        uint4 w0, w1;
        w0.x = (unsigned)f2bf(pig[0])  | ((unsigned)f2bf(pig[1])  << 16);
        w0.y = (unsigned)f2bf(pig[2])  | ((unsigned)f2bf(pig[3])  << 16);
        w0.z = (unsigned)f2bf(pig[4])  | ((unsigned)f2bf(pig[5])  << 16);
        w0.w = (unsigned)f2bf(pig[6])  | ((unsigned)f2bf(pig[7])  << 16);
        w1.x = (unsigned)f2bf(pig[8])  | ((unsigned)f2bf(pig[9])  << 16);
        w1.y = (unsigned)f2bf(pig[10]) | ((unsigned)f2bf(pig[11]) << 16);
        w1.z = (unsigned)f2bf(pig[12]) | ((unsigned)f2bf(pig[13]) << 16);
        w1.w = (unsigned)f2bf(pig[14]) | ((unsigned)f2bf(pig[15]) << 16);
        *(uint4*)(PiGs + ob) = w0;
        *(uint4*)(PiGs + ob + 8) = w1;
      }
      float gwp = 0.f;
      #pragma unroll
      for (int tt = 0; tt < 4; tt++) {
        int i = w*64 + tt*16 + il;
        float ui = u[i];
        #pragma unroll
        for (int kk = 0; kk < 4; kk++) {
          int k = q*4 + kk;
          gwp += creg[tt][kk]*(ui*bf2f(KT[k*KST + i])*vr[k]);
        }
      }
      #pragma unroll
      for (int off = 1; off < 64; off <<= 1) gwp += __shfl_xor(gwp, off);
      if (lane == 0) sred[w][0] = gwp;
      __syncthreads();
      if (t == 0) {
        float S = 0.f;
        #pragma unroll
        for (int w2 = 0; w2 < 8; w2++) S += sred[w2][0];
        gwv[bh*8 + m] = S;
      }
    }
  }
}

// ---------------- alpha ----------------
__global__ void k_alpha(const float* __restrict__ gw, float* __restrict__ alpha) {
  int t = threadIdx.x;
  float gg = gw[t];
  float sc = expf(-(gg*gg));
  float s = sc;
  s += __shfl_xor(s, 1); s += __shfl_xor(s, 2); s += __shfl_xor(s, 4);
  alpha[t] = sc / fmaxf(s, 1e-8f);
}

// ---------------- Q GEMM (MFMA bf16) + alpha-fold + fused normalize + log ----------------
__global__ __launch_bounds__(256) void k_qgemm(const unsigned short* __restrict__ PiGs,
                       const unsigned short* __restrict__ Pis, const float* __restrict__ alpha,
                       float* __restrict__ out) {
  int bid = blockIdx.x;
  int blk = (bid & 7)*128 + (bid >> 3);
  int strip = blk & 15, bh = blk >> 4;
  int i0 = strip*32;
  __shared__ unsigned short As[32*128];   // 8 KB, XOR-swizzled rows
  __shared__ unsigned short Bs[128*128];  // 32 KB, XOR-swizzled rows
  __shared__ float rsum[4][32];
  __shared__ float als[8];
  int t = threadIdx.x;
  int w = t >> 6, lane = t & 63;
  if (t < 8) als[t] = alpha[bh*8 + t];
  __syncthreads();
  const unsigned short* Ab = PiGs + ((size_t)bh*NN + i0)*128;
  #pragma unroll
  for (int q = 0; q < 2; q++) {
    int idx = q*256 + t;
    int r = idx >> 4, sg = idx & 15;
    float4 v = *(const float4*)(Ab + r*128 + sg*8);
    u16x8 hv = *(u16x8*)&v;
    float a = als[sg >> 1];
    u16x8 o;
    #pragma unroll
    for (int e = 0; e < 8; e++) o[e] = f2bf(bf2f(hv[e])*a);
    *(u16x8*)&As[r*128 + (sg ^ (r & 7))*8] = o;
  }
  f32x4 acc[4][2][2] = {};
  const unsigned short* Bb = Pis + (size_t)bh*NN*128;
  for (int c = 0; c < 4; c++) {
    __syncthreads();
    #pragma unroll
    for (int q = 0; q < 8; q++) {
      int idx = q*256 + t;
      int r = idx >> 4, sg = idx & 15;
      float4 v = *(const float4*)(Bb + (size_t)(c*128 + r)*128 + sg*8);
      *(float4*)&Bs[r*128 + (sg ^ (r & 7))*8] = v;
    }
    __syncthreads();
    int col0 = w*32;
    #pragma unroll
    for (int ks = 0; ks < 4; ks++) {
      int slot = (ks*4 + (lane >> 4)) ^ (lane & 7);
      int la = lane & 15;
      bf16x8 a0 = *(bf16x8*)&As[la*128 + slot*8];
      bf16x8 a1 = *(bf16x8*)&As[(la+16)*128 + slot*8];
      bf16x8 b0 = *(bf16x8*)&Bs[(col0+la)*128 + slot*8];
      bf16x8 b1 = *(bf16x8*)&Bs[(col0+la+16)*128 + slot*8];
      acc[c][0][0] = __builtin_amdgcn_mfma_f32_16x16x32_bf16(a0, b0, acc[c][0][0], 0, 0, 0);
      acc[c][1][0] = __builtin_amdgcn_mfma_f32_16x16x32_bf16(a1, b0, acc[c][1][0], 0, 0, 0);
      acc[c][0][1] = __builtin_amdgcn_mfma_f32_16x16x32_bf16(a0, b1, acc[c][0][1], 0, 0, 0);
      acc[c][1][1] = __builtin_amdgcn_mfma_f32_16x16x32_bf16(a1, b1, acc[c][1][1], 0, 0, 0);
    }
  }
  float part[2][4];
  #pragma unroll
  for (int mt = 0; mt < 2; mt++) {
    #pragma unroll
    for (int rg = 0; rg < 4; rg++) {
      float s = 0.f;
      #pragma unroll
      for (int c = 0; c < 4; c++) {
        #pragma unroll
        for (int nt = 0; nt < 2; nt++) s += fmaxf(acc[c][mt][nt][rg], 1e-8f);
      }
      s += __shfl_xor(s, 1); s += __shfl_xor(s, 2);
      s += __shfl_xor(s, 4); s += __shfl_xor(s, 8);
      part[mt][rg] = s;
    }
  }
  if ((lane & 15) == 0) {
    int rgrp = lane >> 4;
    #pragma unroll
    for (int mt = 0; mt < 2; mt++)
      #pragma unroll
      for (int rg = 0; rg < 4; rg++)
        rsum[w][mt*16 + rgrp*4 + rg] = part[mt][rg];
  }
  __syncthreads();
  float invr[2][4];
  #pragma unroll
  for (int mt = 0; mt < 2; mt++) {
    #pragma unroll
    for (int rg = 0; rg < 4; rg++) {
      int row = mt*16 + (lane >> 4)*4 + rg;
      invr[mt][rg] = 1.f / (rsum[0][row] + rsum[1][row] + rsum[2][row] + rsum[3][row]);
    }
  }
  float* Qb = out + (size_t)QOFF + ((size_t)bh*NN + i0)*NN;
  float* Lb = out + ((size_t)bh*NN + i0)*NN;
  #pragma unroll
  for (int c = 0; c < 4; c++) {
    #pragma unroll
    for (int mt = 0; mt < 2; mt++) {
      #pragma unroll
      for (int nt = 0; nt < 2; nt++) {
        #pragma unroll
        for (int rg = 0; rg < 4; rg++) {
          int row = mt*16 + (lane >> 4)*4 + rg;
          int col = c*128 + w*32 + nt*16 + (lane & 15);
          float v = fmaxf(acc[c][mt][nt][rg], 1e-8f)*invr[mt][rg];
          Qb[(size_t)row*NN + col] = v;
          Lb[(size_t)row*NN + col] = __logf(v);
        }
      }
    }
  }
}

// ---------------- slot usage ----------------
__global__ __launch_bounds__(256) void k_usage(const float* __restrict__ z, const float* __restrict__ Wp,
                        const float* __restrict__ bp, float* __restrict__ partial) {
  __shared__ float wps[256][9];
  __shared__ float red[256][8];
  int t = threadIdx.x;
  {
    float4 a = *(const float4*)(Wp + t*8);
    float4 b = *(const float4*)(Wp + t*8 + 4);
    wps[t][0]=a.x; wps[t][1]=a.y; wps[t][2]=a.z; wps[t][3]=a.w;
    wps[t][4]=b.x; wps[t][5]=b.y; wps[t][6]=b.z; wps[t][7]=b.w;
  }
  __syncthreads();
  int row = blockIdx.x*256 + t;
  const float* zr = z + (size_t)row*ND;
  float acc[8] = {};
  for (int d0 = 0; d0 < ND; d0 += 4) {
    float4 v = *(const float4*)(zr + d0);
    #pragma unroll
    for (int m = 0; m < 8; m++) {
      acc[m] += v.x*wps[d0][m] + v.y*wps[d0+1][m] + v.z*wps[d0+2][m] + v.w*wps[d0+3][m];
    }
  }
  float mx = -1e30f;
  #pragma unroll
  for (int m = 0; m < 8; m++) { acc[m] += bp[m]; mx = fmaxf(mx, acc[m]); }
  float s = 0.f;
  #pragma unroll
  for (int m = 0; m < 8; m++) { acc[m] = expf(acc[m]-mx); s += acc[m]; }
  float inv = 1.f/s;
  #pragma unroll
  for (int m = 0; m < 8; m++) red[t][m] = acc[m]*inv;
  __syncthreads();
  for (int q = 128; q > 0; q >>= 1) {
    if (t < q) { for (int m = 0; m < 8; m++) red[t][m] += red[t+q][m]; }
    __syncthreads();
  }
  if (t < 8) partial[blockIdx.x*8 + t] = red[0][t];
}

// ---------------- final scalar ----------------
__global__ void k_final(const float* __restrict__ greg, const float* __restrict__ partial,
                        float* __restrict__ out) {
  if (threadIdx.x == 0) {
    float us[8] = {};
    for (int b = 0; b < 16; b++)
      for (int m = 0; m < 8; m++) us[m] += partial[b*8 + m];
    float kl = 0.f;
    for (int m = 0; m < 8; m++) {
      float u = us[m] / (float)BN;
      kl += u*logf(fmaxf(u, 1e-8f)*(float)NM);
    }
    out[33554432] = greg[0] + 0.01f*kl;
  }
}

extern "C" void kernel_launch(void* const* d_in, const int* in_sizes, int n_in,
                              void* d_out, int out_size, void* d_ws, size_t ws_size,
                              hipStream_t stream) {
  const float* xd = (const float*)d_in[0];
  const float* xn = (const float*)d_in[1];
  const float* W1 = (const float*)d_in[2];
  const float* b1 = (const float*)d_in[3];
  const float* W2 = (const float*)d_in[4];
  const float* b2 = (const float*)d_in[5];
  const float* Wp = (const float*)d_in[6];
  const float* bp = (const float*)d_in[7];
  const float* Up = (const float*)d_in[8];
  float* out = (float*)d_out;
  float* ws  = (float*)d_ws;

  float* z   = ws + 0;                                    // 1,048,576 f
  float* hid = ws + 1048576;                              // 1,048,576 f
  float* zh  = ws + 2097152;                              // 1,048,576 f
  unsigned short* PiGs = (unsigned short*)(ws + 3145728); // 4,194,304 u16
  unsigned short* Pis  = (unsigned short*)(ws + 5242880); // 4,194,304 u16
  float* gw    = ws + 7340032;
  float* alpha = ws + 7340544;
  float* G     = ws + 7341056;
  float* DG    = ws + 7343104;
  float* greg  = ws + 7345152;
  float* partial = ws + 7345153;
  float* rsb   = ws + 7345664;    // 32768 f
  float* rqb   = ws + 7378432;    // 32768 f

  // d_out doubles as scratch:
  //  - bias region: P (bf16, 33.5 MB) until k_dp; then qgemm writes bias_log
  //  - Q region: DP (bf16) + DPsq (bf16) = 67 MB; qgemm overwrites with Q
  unsigned short* P16 = (unsigned short*)out;
  unsigned short* DPb = (unsigned short*)(out + QOFF);
  unsigned short* DPq = DPb + (size_t)16777216;

  k_mlp1<<<dim3(4, 64), 256, 0, stream>>>(xd, xn, W1, b1, hid);
  k_mlp2<<<dim3(4, 64), 256, 0, stream>>>(hid, W2, b2, z);
  k_usage<<<16, 256, 0, stream>>>(z, Wp, bp, partial);
  k_zhnorm<<<4096, 256, 0, stream>>>(z, zh);
  k_affinity<<<1024, 256, 0, stream>>>(zh, P16);
  k_dp<<<1024, 256, 0, stream>>>(P16, DPb, DPq, rsb, rqb);
  k_slots<<<1, 256, 0, stream>>>(Up, G, DG, greg);
  k_gw<<<512, 512, 0, stream>>>(DPb, DPq, rsb, rqb, G, DG, PiGs, Pis, gw);
  k_alpha<<<1, 512, 0, stream>>>(gw, alpha);
  k_qgemm<<<1024, 256, 0, stream>>>(PiGs, Pis, alpha, out);
  k_final<<<1, 64, 0, stream>>>(greg, partial, out);
}

// Round 8
// 508.463 us; speedup vs baseline: 1.2744x; 1.2744x over previous
//
#include <hip/hip_runtime.h>
#include <cstdint>
#include <cstddef>

#define NB 8
#define NN 512
#define ND 256
#define NH 8
#define NM 8
#define NK 16
#define NR 8
#define NDH 32
#define BN (NB*NN)           // 4096 rows
#define BH (NB*NH)           // 64
#define BHN (BH*NN)          // 32768
#define BHM (BH*NM)          // 512
#define QOFF 16777216        // B*H*N*N

typedef __attribute__((ext_vector_type(8))) short bf16x8;
typedef __attribute__((ext_vector_type(8))) unsigned short u16x8;
typedef __attribute__((ext_vector_type(4))) float f32x4;

__device__ inline unsigned short f2bf(float x) {
  union { float f; unsigned u; } c; c.f = x;
  unsigned r = c.u + 0x7FFFu + ((c.u >> 16) & 1u);
  return (unsigned short)(r >> 16);
}
__device__ inline float bf2f(unsigned short x) {
  union { unsigned u; float f; } c; c.u = ((unsigned)x) << 16; return c.f;
}
__device__ inline float bflo(unsigned w2) {
  union { unsigned u; float f; } c; c.u = w2 << 16; return c.f;
}
__device__ inline float bfhi(unsigned w2) {
  union { unsigned u; float f; } c; c.u = w2 & 0xFFFF0000u; return c.f;
}

// ---------------- MLP: 64x64 tile, 4x4 per thread ----------------
__global__ __launch_bounds__(256) void k_mlp1(const float* __restrict__ xd, const float* __restrict__ xn,
                       const float* __restrict__ W1, const float* __restrict__ b1,
                       float* __restrict__ hid) {
  __shared__ float As[16][68];   // [k][i]
  __shared__ float Bs[16][68];   // [k][j]
  int t = threadIdx.x;
  int col0 = blockIdx.x * 64;
  int row0 = blockIdx.y * 64;
  int ar = t >> 2, ak = (t & 3) * 4;
  int bk = t >> 4, bc = (t & 15) * 4;
  int ty = t >> 4, tx = t & 15;
  float acc[4][4] = {};
  for (int k0 = 0; k0 < 2*ND; k0 += 16) {
    int gk = k0 + ak;
    const float* src = (gk < ND) ? (xd + (size_t)(row0+ar)*ND + gk)
                                 : (xn + (size_t)(row0+ar)*ND + (gk-ND));
    float4 av = *(const float4*)src;
    As[ak+0][ar] = av.x; As[ak+1][ar] = av.y; As[ak+2][ar] = av.z; As[ak+3][ar] = av.w;
    float4 bv = *(const float4*)(W1 + (size_t)(k0+bk)*ND + col0 + bc);
    *(float4*)&Bs[bk][bc] = bv;
    __syncthreads();
    #pragma unroll
    for (int kk = 0; kk < 16; kk++) {
      float4 a = *(const float4*)&As[kk][ty*4];
      float4 b = *(const float4*)&Bs[kk][tx*4];
      acc[0][0] += a.x*b.x; acc[0][1] += a.x*b.y; acc[0][2] += a.x*b.z; acc[0][3] += a.x*b.w;
      acc[1][0] += a.y*b.x; acc[1][1] += a.y*b.y; acc[1][2] += a.y*b.z; acc[1][3] += a.y*b.w;
      acc[2][0] += a.z*b.x; acc[2][1] += a.z*b.y; acc[2][2] += a.z*b.z; acc[2][3] += a.z*b.w;
      acc[3][0] += a.w*b.x; acc[3][1] += a.w*b.y; acc[3][2] += a.w*b.z; acc[3][3] += a.w*b.w;
    }
    __syncthreads();
  }
  float4 bb = *(const float4*)(b1 + col0 + tx*4);
  #pragma unroll
  for (int a = 0; a < 4; a++) {
    float4 o;
    o.x = fmaxf(acc[a][0] + bb.x, 0.f);
    o.y = fmaxf(acc[a][1] + bb.y, 0.f);
    o.z = fmaxf(acc[a][2] + bb.z, 0.f);
    o.w = fmaxf(acc[a][3] + bb.w, 0.f);
    *(float4*)(hid + (size_t)(row0+ty*4+a)*ND + col0 + tx*4) = o;
  }
}

__global__ __launch_bounds__(256) void k_mlp2(const float* __restrict__ hidp,
                       const float* __restrict__ W2, const float* __restrict__ b2,
                       float* __restrict__ z) {
  __shared__ float As[16][68];
  __shared__ float Bs[16][68];
  int t = threadIdx.x;
  int col0 = blockIdx.x * 64;
  int row0 = blockIdx.y * 64;
  int ar = t >> 2, ak = (t & 3) * 4;
  int bk = t >> 4, bc = (t & 15) * 4;
  int ty = t >> 4, tx = t & 15;
  float acc[4][4] = {};
  for (int k0 = 0; k0 < ND; k0 += 16) {
    float4 av = *(const float4*)(hidp + (size_t)(row0+ar)*ND + k0 + ak);
    As[ak+0][ar] = av.x; As[ak+1][ar] = av.y; As[ak+2][ar] = av.z; As[ak+3][ar] = av.w;
    float4 bv = *(const float4*)(W2 + (size_t)(k0+bk)*ND + col0 + bc);
    *(float4*)&Bs[bk][bc] = bv;
    __syncthreads();
    #pragma unroll
    for (int kk = 0; kk < 16; kk++) {
      float4 a = *(const float4*)&As[kk][ty*4];
      float4 b = *(const float4*)&Bs[kk][tx*4];
      acc[0][0] += a.x*b.x; acc[0][1] += a.x*b.y; acc[0][2] += a.x*b.z; acc[0][3] += a.x*b.w;
      acc[1][0] += a.y*b.x; acc[1][1] += a.y*b.y; acc[1][2] += a.y*b.z; acc[1][3] += a.y*b.w;
      acc[2][0] += a.z*b.x; acc[2][1] += a.z*b.y; acc[2][2] += a.z*b.z; acc[2][3] += a.z*b.w;
      acc[3][0] += a.w*b.x; acc[3][1] += a.w*b.y; acc[3][2] += a.w*b.z; acc[3][3] += a.w*b.w;
    }
    __syncthreads();
  }
  float4 bb = *(const float4*)(b2 + col0 + tx*4);
  #pragma unroll
  for (int a = 0; a < 4; a++) {
    float4 o;
    o.x = acc[a][0] + bb.x; o.y = acc[a][1] + bb.y;
    o.z = acc[a][2] + bb.z; o.w = acc[a][3] + bb.w;
    *(float4*)(z + (size_t)(row0+ty*4+a)*ND + col0 + tx*4) = o;
  }
}

// ---------------- zh normalize ----------------
__global__ void k_zhnorm(const float* __restrict__ z, float* __restrict__ zh) {
  int idx = blockIdx.x*256 + threadIdx.x;
  int d = idx & 31;
  int n = (idx >> 5) & (NN-1);
  int h = (idx >> 14) & (NH-1);
  int b = idx >> 17;
  float v = z[(size_t)(b*NN + n)*ND + h*NDH + d];
  float ss = v*v;
  #pragma unroll
  for (int m = 1; m < 32; m <<= 1) ss += __shfl_xor(ss, m);
  zh[idx] = v / fmaxf(sqrtf(ss), 1e-8f);
}

// ---------------- affinity + softmax -> P (bf16) ----------------
__global__ __launch_bounds__(256) void k_affinity(const float* __restrict__ zh, unsigned short* __restrict__ P) {
  int blk = blockIdx.x;               // 64 bh * 16 rowtiles
  int rt = blk & 15, bh = blk >> 4;
  int r0 = rt*32;
  const float* base = zh + (size_t)bh*NN*NDH;
  __shared__ float qs[32][33];
  __shared__ float ks[32][36];        // [d][s]
  int t = threadIdx.x;
  int sr = t >> 3, dq = (t & 7)*4;
  {
    float4 v = *(const float4*)(base + (size_t)(r0+sr)*NDH + dq);
    qs[sr][dq] = v.x; qs[sr][dq+1] = v.y; qs[sr][dq+2] = v.z; qs[sr][dq+3] = v.w;
  }
  int cr = t >> 3;
  int cq = t & 7;
  float acc[16][4];
  #pragma unroll
  for (int ti = 0; ti < 16; ti++) { acc[ti][0]=0; acc[ti][1]=0; acc[ti][2]=0; acc[ti][3]=0; }
  for (int ti = 0; ti < 16; ti++) {
    int s0 = ti*32;
    __syncthreads();
    {
      float4 v = *(const float4*)(base + (size_t)(s0+sr)*NDH + dq);
      ks[dq+0][sr] = v.x; ks[dq+1][sr] = v.y; ks[dq+2][sr] = v.z; ks[dq+3][sr] = v.w;
    }
    __syncthreads();
    #pragma unroll
    for (int d = 0; d < 32; d++) {
      float qv = qs[cr][d];
      float4 kv = *(const float4*)&ks[d][cq*4];
      acc[ti][0] += qv*kv.x; acc[ti][1] += qv*kv.y;
      acc[ti][2] += qv*kv.z; acc[ti][3] += qv*kv.w;
    }
  }
  int gr = r0 + cr;
  float mx = -1e30f;
  #pragma unroll
  for (int ti = 0; ti < 16; ti++) {
    #pragma unroll
    for (int j = 0; j < 4; j++) {
      int s = ti*32 + cq*4 + j;
      float v = (s == gr) ? -1e9f : acc[ti][j]*0.0625f;
      acc[ti][j] = v;
      mx = fmaxf(mx, v);
    }
  }
  mx = fmaxf(mx, __shfl_xor(mx, 1));
  mx = fmaxf(mx, __shfl_xor(mx, 2));
  mx = fmaxf(mx, __shfl_xor(mx, 4));
  float sum = 0.f;
  #pragma unroll
  for (int ti = 0; ti < 16; ti++) {
    #pragma unroll
    for (int j = 0; j < 4; j++) { float e = expf(acc[ti][j]-mx); acc[ti][j] = e; sum += e; }
  }
  sum += __shfl_xor(sum,1); sum += __shfl_xor(sum,2); sum += __shfl_xor(sum,4);
  float inv = 1.f/sum;
  unsigned short* prow = P + ((size_t)(bh*NN) + gr)*NN;
  #pragma unroll
  for (int ti = 0; ti < 16; ti++) {
    uint2 pk;
    pk.x = (unsigned)f2bf(acc[ti][0]*inv) | ((unsigned)f2bf(acc[ti][1]*inv) << 16);
    pk.y = (unsigned)f2bf(acc[ti][2]*inv) | ((unsigned)f2bf(acc[ti][3]*inv) << 16);
    *(uint2*)(prow + ti*32 + cq*4) = pk;
  }
}

// ---------------- DP: symmetrize + row-normalize -> DPt,DQt in MFMA-fragment layout ----------------
// layout: elem(i,j) -> ((j>>5)*32 + (i>>4))*512 + (i&15)*32 + (j&31)
// so a wave's B-fragment (16 rows x 32 cols) is 1 KB contiguous.
__global__ __launch_bounds__(256) void k_dp(const unsigned short* __restrict__ P,
                       unsigned short* __restrict__ DPt, unsigned short* __restrict__ DQt,
                       float* __restrict__ rs, float* __restrict__ rq) {
  int blk = blockIdx.x;               // 64*16
  int rt = blk & 15, bh = blk >> 4;
  int r0 = rt*32;
  const unsigned short* Pb = P + (size_t)bh*NN*NN;
  unsigned short* Dbase = DPt + (size_t)bh*NN*NN;
  unsigned short* Qbase = DQt + (size_t)bh*NN*NN;
  __shared__ float Bs[32][33];
  int t = threadIdx.x;
  int r = t >> 3, q4 = (t & 7)*4;
  int i = r0 + r;
  int b = i >> 4, il = i & 15;
  float pn[16][4];
  float rowacc = 0.f;
  for (int ti = 0; ti < 16; ti++) {
    int s0 = ti*32;
    __syncthreads();
    {
      uint2 v = *(const uint2*)(Pb + (size_t)(s0+r)*NN + r0 + q4);
      Bs[r][q4+0] = bf2f((unsigned short)(v.x & 0xFFFF));
      Bs[r][q4+1] = bf2f((unsigned short)(v.x >> 16));
      Bs[r][q4+2] = bf2f((unsigned short)(v.y & 0xFFFF));
      Bs[r][q4+3] = bf2f((unsigned short)(v.y >> 16));
    }
    uint2 av = *(const uint2*)(Pb + (size_t)i*NN + s0 + q4);
    __syncthreads();
    float a0 = bf2f((unsigned short)(av.x & 0xFFFF));
    float a1 = bf2f((unsigned short)(av.x >> 16));
    float a2 = bf2f((unsigned short)(av.y & 0xFFFF));
    float a3 = bf2f((unsigned short)(av.y >> 16));
    float p0 = fmaxf(0.5f*(a0 + Bs[q4+0][r]), 1e-8f);
    float p1 = fmaxf(0.5f*(a1 + Bs[q4+1][r]), 1e-8f);
    float p2 = fmaxf(0.5f*(a2 + Bs[q4+2][r]), 1e-8f);
    float p3 = fmaxf(0.5f*(a3 + Bs[q4+3][r]), 1e-8f);
    pn[ti][0]=p0; pn[ti][1]=p1; pn[ti][2]=p2; pn[ti][3]=p3;
    rowacc += p0+p1+p2+p3;
  }
  rowacc += __shfl_xor(rowacc,1); rowacc += __shfl_xor(rowacc,2); rowacc += __shfl_xor(rowacc,4);
  float inv = 1.f / fmaxf(rowacc, 1e-8f);
  float rsv = 0.f, rqv = 0.f;
  #pragma unroll
  for (int ti = 0; ti < 16; ti++) {
    float o0 = fmaxf(1.f - pn[ti][0]*inv, 0.f);
    float o1 = fmaxf(1.f - pn[ti][1]*inv, 0.f);
    float o2 = fmaxf(1.f - pn[ti][2]*inv, 0.f);
    float o3 = fmaxf(1.f - pn[ti][3]*inv, 0.f);
    rsv += o0+o1+o2+o3;
    rqv += o0*o0 + o1*o1 + o2*o2 + o3*o3;
    // fragment-major address: j = ti*32 + q4 .. +3
    size_t fo = ((size_t)(ti*32 + b) << 9) + il*32 + q4;
    uint2 pk;
    pk.x = (unsigned)f2bf(o0) | ((unsigned)f2bf(o1) << 16);
    pk.y = (unsigned)f2bf(o2) | ((unsigned)f2bf(o3) << 16);
    *(uint2*)(Dbase + fo) = pk;
    uint2 qk;
    qk.x = (unsigned)f2bf(o0*o0) | ((unsigned)f2bf(o1*o1) << 16);
    qk.y = (unsigned)f2bf(o2*o2) | ((unsigned)f2bf(o3*o3) << 16);
    *(uint2*)(Qbase + fo) = qk;
  }
  rsv += __shfl_xor(rsv,1); rsv += __shfl_xor(rsv,2); rsv += __shfl_xor(rsv,4);
  rqv += __shfl_xor(rqv,1); rqv += __shfl_xor(rqv,2); rqv += __shfl_xor(rqv,4);
  if ((t & 7) == 0) {
    rs[bh*NN + i] = rsv;
    rq[bh*NN + i] = rqv;
  }
}

// ---------------- slot graphs: G, g_reg, DG ----------------
__global__ void k_slots(const float* __restrict__ Up, float* __restrict__ G,
                        float* __restrict__ DG, float* __restrict__ greg) {
  __shared__ float U[NM*NK*NR];
  __shared__ float Gs[NM*NK*NK];
  __shared__ float rsx[NM*NK];
  __shared__ float vn[NM];
  __shared__ float gram[NM*NM];
  int t = threadIdx.x;
  for (int i = t; i < NM*NK*NR; i += 256) {
    float x = Up[i];
    U[i] = fmaxf(x, 0.f) + log1pf(expf(-fabsf(x)));
  }
  __syncthreads();
  for (int i = t; i < NM*NK*NK; i += 256) {
    int m = i >> 8, k = (i >> 4) & 15, j = i & 15;
    float acc = 0.f;
    #pragma unroll
    for (int r = 0; r < NR; r++) acc += U[(m*NK+k)*NR + r]*U[(m*NK+j)*NR + r];
    Gs[i] = acc;
  }
  __syncthreads();
  for (int i = t; i < NM*NK; i += 256) {
    float s = 0.f;
    #pragma unroll
    for (int j = 0; j < NK; j++) s += Gs[i*NK + j];
    rsx[i] = fmaxf(s, 1e-8f);
  }
  __syncthreads();
  for (int i = t; i < NM*NK*NK; i += 256) { Gs[i] /= rsx[i >> 4]; G[i] = Gs[i]; }
  __syncthreads();
  for (int i = t; i < NM; i += 256) {
    float s = 0.f;
    for (int j = 0; j < NK*NK; j++) { float g = Gs[i*NK*NK + j]; s += g*g; }
    vn[i] = fmaxf(sqrtf(s), 1e-8f);
  }
  __syncthreads();
  for (int i = t; i < NM*NM; i += 256) {
    int a = i >> 3, b = i & 7;
    float s = 0.f;
    for (int j = 0; j < NK*NK; j++) s += Gs[a*NK*NK + j]*Gs[b*NK*NK + j];
    gram[i] = s / (vn[a]*vn[b]);
  }
  __syncthreads();
  if (t == 0) {
    float s = 0.f;
    for (int i = 0; i < NM*NM; i++) if ((i >> 3) != (i & 7)) s += gram[i];
    greg[0] = 0.1f * s / (float)(NM*(NM-1));
  }
  for (int i = t; i < NM*NK*NK; i += 256) {
    int m = i >> 8, k = (i >> 4) & 15, j = i & 15;
    float dk = fmaxf(Gs[m*NK*NK + k*NK + k], 1e-8f);
    float dj = fmaxf(Gs[m*NK*NK + j*NK + j], 1e-8f);
    float den = fmaxf(sqrtf(dk*dj), 1e-8f);
    float c = fminf(fmaxf(Gs[i]/den, -1.f), 1.f);
    float d = fmaxf(1.f - c, 0.f);
    if (k == j) d = 0.f;
    DG[i] = d;
  }
}

// ---------------- fused GW: fragment-major direct loads, no staging, no creg ----------------
#define KST 522     // KT row stride (u16): bf16 K matrix [16][512]
#define PSTR 516    // PiT row stride (u16): word-stride 258 = 2 mod 32 -> 2-way banks
__global__ __launch_bounds__(512, 2) void k_gw(
    const unsigned short* __restrict__ DPt,   // fragment-major bf16
    const unsigned short* __restrict__ DQt,   // DP^2, same layout
    const float* __restrict__ rs, const float* __restrict__ rq,
    const float* __restrict__ Gm, const float* __restrict__ DGm,
    unsigned short* __restrict__ PiGs, unsigned short* __restrict__ Pis,
    float* __restrict__ gwv) {
  int blk = blockIdx.x;
  int xcd = blk & 7, seq = blk >> 3;
  int bh = xcd*8 + (seq >> 3);                // 8 m of one bh share an XCD
  int m  = seq & 7;
  __shared__ __align__(16) unsigned short KT[16*KST];      // 16.7 KB
  __shared__ __align__(16) unsigned short PiT[16*PSTR];    // 16.5 KB
  __shared__ __align__(16) float u[512];
  __shared__ __align__(16) float vv[16];
  __shared__ float ml[16], t2s[16], dgrow[16];
  __shared__ float Gsm[16][17], DGsm[16][17];
  __shared__ float sred[8][16];
  int t = threadIdx.x;
  int lane = t & 63, w = t >> 6;
  int il = lane & 15, q = lane >> 4;
  int g = t >> 4, kc = t & 15;
  if (t < 256) { Gsm[t>>4][t&15] = Gm[m*256 + t]; DGsm[t>>4][t&15] = DGm[m*256 + t]; }
  __syncthreads();
  if (t < 16) {
    float s = 0.f;
    #pragma unroll
    for (int l = 0; l < 16; l++) s += DGsm[t][l];
    dgrow[t] = s;
  }
  const unsigned short* Dbase = DPt + (size_t)bh*NN*NN;
  const unsigned short* Qbase = DQt + (size_t)bh*NN*NN;
  float rsv = rs[bh*NN + t]*(1.f/8192.f);
  float rqv = rq[bh*NN + t]*(1.f/512.f);
  float Kt[16];
  float ut = 0.f;
  int lo = il*32 + q*8;       // lane offset within a 512-elem fragment tile
  for (int itr = 0; itr < 3; ++itr) {
    if (t < 16) {
      float s = 0.f;
      #pragma unroll
      for (int l = 0; l < 16; l++) { float d = DGsm[t][l]; s += d*d*((itr == 0) ? (1.f/16.f) : ml[l]); }
      t2s[t] = s;
    }
    __syncthreads();
    if (itr == 0) {
      // closed form: W uniform -> cross = rsv*dgrow, t1 = rqv
      #pragma unroll
      for (int k = 0; k < 16; k++) {
        float c = fmaxf(rqv + t2s[k] - 2.f*rsv*dgrow[k], 0.f);
        float e = fmaxf(__expf(-20.f*c), 1e-12f);
        Kt[k] = e;
        KT[k*KST + t] = f2bf(e);
      }
    } else {
      // ---- single sweep: W = PiT x DP^T, V = PiT x DPsq^T, frags direct from global ----
      f32x4 aW0={0,0,0,0}, aW1={0,0,0,0}, aW2={0,0,0,0}, aW3={0,0,0,0};
      f32x4 aV0={0,0,0,0}, aV1={0,0,0,0}, aV2={0,0,0,0}, aV3={0,0,0,0};
      #pragma unroll 2
      for (int p = 0; p < 16; p++) {
        bf16x8 af = *(const bf16x8*)&PiT[il*PSTR + p*32 + q*8];
        size_t fb = ((size_t)(p*32 + w*4) << 9) + lo;
        bf16x8 w0 = *(const bf16x8*)(Dbase + fb);
        bf16x8 w1 = *(const bf16x8*)(Dbase + fb + 512);
        bf16x8 w2 = *(const bf16x8*)(Dbase + fb + 1024);
        bf16x8 w3 = *(const bf16x8*)(Dbase + fb + 1536);
        bf16x8 v0 = *(const bf16x8*)(Qbase + fb);
        bf16x8 v1 = *(const bf16x8*)(Qbase + fb + 512);
        bf16x8 v2 = *(const bf16x8*)(Qbase + fb + 1024);
        bf16x8 v3 = *(const bf16x8*)(Qbase + fb + 1536);
        aW0 = __builtin_amdgcn_mfma_f32_16x16x32_bf16(af, w0, aW0, 0, 0, 0);
        aW1 = __builtin_amdgcn_mfma_f32_16x16x32_bf16(af, w1, aW1, 0, 0, 0);
        aW2 = __builtin_amdgcn_mfma_f32_16x16x32_bf16(af, w2, aW2, 0, 0, 0);
        aW3 = __builtin_amdgcn_mfma_f32_16x16x32_bf16(af, w3, aW3, 0, 0, 0);
        aV0 = __builtin_amdgcn_mfma_f32_16x16x32_bf16(af, v0, aV0, 0, 0, 0);
        aV1 = __builtin_amdgcn_mfma_f32_16x16x32_bf16(af, v1, aV1, 0, 0, 0);
        aV2 = __builtin_amdgcn_mfma_f32_16x16x32_bf16(af, v2, aV2, 0, 0, 0);
        aV3 = __builtin_amdgcn_mfma_f32_16x16x32_bf16(af, v3, aV3, 0, 0, 0);
      }
      // epilogue: t1 = rowsum(V); cross = W x DG; C -> KT(bf16)
      #pragma unroll
      for (int tt = 0; tt < 4; tt++) {
        f32x4 av = (tt==0)?aW0:((tt==1)?aW1:((tt==2)?aW2:aW3));
        f32x4 bv = (tt==0)?aV0:((tt==1)?aV1:((tt==2)?aV2:aV3));
        float tv = bv[0]+bv[1]+bv[2]+bv[3];
        tv += __shfl_xor(tv, 16); tv += __shfl_xor(tv, 32);
        float pc[16];
        #pragma unroll
        for (int k = 0; k < 16; k++) {
          pc[k] = av[0]*DGsm[k][q*4+0] + av[1]*DGsm[k][q*4+1]
                + av[2]*DGsm[k][q*4+2] + av[3]*DGsm[k][q*4+3];
        }
        #pragma unroll
        for (int k = 0; k < 16; k++) { pc[k] += __shfl_xor(pc[k], 16); pc[k] += __shfl_xor(pc[k], 32); }
        int i = w*64 + tt*16 + il;
        #pragma unroll
        for (int kk = 0; kk < 4; kk++) {
          int k = q*4 + kk;
          float c = fmaxf(tv + t2s[k] - 2.f*pc[k], 0.f);
          KT[k*KST + i] = f2bf(fmaxf(__expf(-20.f*c), 1e-12f));
        }
      }
      __syncthreads();
      // cache own K column in registers
      #pragma unroll
      for (int k = 0; k < 16; k++) Kt[k] = bf2f(KT[k*KST + t]);
    }
    __syncthreads();
    // ---- sinkhorn: 10 iters; u-update register-only, v-update vectorized ----
    if (t < 16) vv[t] = 1.f/16.f;
    __syncthreads();
    for (int si = 0; si < 10; si++) {
      float4 va = *(const float4*)&vv[0];
      float4 vb = *(const float4*)&vv[4];
      float4 vc = *(const float4*)&vv[8];
      float4 vd = *(const float4*)&vv[12];
      float s = Kt[0]*va.x + Kt[1]*va.y + Kt[2]*va.z + Kt[3]*va.w
              + Kt[4]*vb.x + Kt[5]*vb.y + Kt[6]*vb.z + Kt[7]*vb.w
              + Kt[8]*vc.x + Kt[9]*vc.y + Kt[10]*vc.z + Kt[11]*vc.w
              + Kt[12]*vd.x + Kt[13]*vd.y + Kt[14]*vd.z + Kt[15]*vd.w;
      ut = (1.f/512.f)/(s + 1e-6f);
      u[t] = ut;
      __syncthreads();
      const unsigned* kp = (const unsigned*)&KT[kc*KST + g*16];
      unsigned k0 = kp[0], k1 = kp[1], k2 = kp[2], k3 = kp[3];
      unsigned k4 = kp[4], k5 = kp[5], k6 = kp[6], k7 = kp[7];
      float4 ua = *(const float4*)&u[g*16];
      float4 ub = *(const float4*)&u[g*16+4];
      float4 uc = *(const float4*)&u[g*16+8];
      float4 ud = *(const float4*)&u[g*16+12];
      float p = bflo(k0)*ua.x + bfhi(k0)*ua.y + bflo(k1)*ua.z + bfhi(k1)*ua.w
              + bflo(k2)*ub.x + bfhi(k2)*ub.y + bflo(k3)*ub.z + bfhi(k3)*ub.w
              + bflo(k4)*uc.x + bfhi(k4)*uc.y + bflo(k5)*uc.z + bfhi(k5)*uc.w
              + bflo(k6)*ud.x + bfhi(k6)*ud.y + bflo(k7)*ud.z + bfhi(k7)*ud.w;
      p += __shfl_xor(p, 16); p += __shfl_xor(p, 32);
      if (lane < 16) sred[w][lane] = p;
      __syncthreads();
      if (t < 16) {
        float S = sred[0][t]+sred[1][t]+sred[2][t]+sred[3][t]
                + sred[4][t]+sred[5][t]+sred[6][t]+sred[7][t];
        float nv = (1.f/16.f)/(S + 1e-6f);
        vv[t] = nv;
        ml[t] = nv*S;        // massl, valid at si==9
      }
      __syncthreads();
    }
    if (itr < 2) {
      // rebuild PiT (bf16) for next iter's MFMA streams
      const unsigned* kp = (const unsigned*)&KT[kc*KST + g*16];
      float4 ua = *(const float4*)&u[g*16];
      float4 ub = *(const float4*)&u[g*16+4];
      float4 uc = *(const float4*)&u[g*16+8];
      float4 ud = *(const float4*)&u[g*16+12];
      float vk = vv[kc];
      unsigned* pp = (unsigned*)&PiT[kc*PSTR + g*16];
      unsigned kx;
      kx = kp[0]; pp[0] = (unsigned)f2bf(ua.x*bflo(kx)*vk) | ((unsigned)f2bf(ua.y*bfhi(kx)*vk) << 16);
      kx = kp[1]; pp[1] = (unsigned)f2bf(ua.z*bflo(kx)*vk) | ((unsigned)f2bf(ua.w*bfhi(kx)*vk) << 16);
      kx = kp[2]; pp[2] = (unsigned)f2bf(ub.x*bflo(kx)*vk) | ((unsigned)f2bf(ub.y*bfhi(kx)*vk) << 16);
      kx = kp[3]; pp[3] = (unsigned)f2bf(ub.z*bflo(kx)*vk) | ((unsigned)f2bf(ub.w*bfhi(kx)*vk) << 16);
      kx = kp[4]; pp[4] = (unsigned)f2bf(uc.x*bflo(kx)*vk) | ((unsigned)f2bf(uc.y*bfhi(kx)*vk) << 16);
      kx = kp[5]; pp[5] = (unsigned)f2bf(uc.z*bflo(kx)*vk) | ((unsigned)f2bf(uc.w*bfhi(kx)*vk) << 16);
      kx = kp[6]; pp[6] = (unsigned)f2bf(ud.x*bflo(kx)*vk) | ((unsigned)f2bf(ud.y*bfhi(kx)*vk) << 16);
      kx = kp[7]; pp[7] = (unsigned)f2bf(ud.z*bflo(kx)*vk) | ((unsigned)f2bf(ud.w*bfhi(kx)*vk) << 16);
      __syncthreads();
    } else {
      // ---- final: Pi/PiG stacks + gw (C from -ln(K)/20, all register-local) ----
      float4 va = *(const float4*)&vv[0];
      float4 vb = *(const float4*)&vv[4];
      float4 vc = *(const float4*)&vv[8];
      float4 vd = *(const float4*)&vv[12];
      float vr[16] = {va.x,va.y,va.z,va.w, vb.x,vb.y,vb.z,vb.w,
                      vc.x,vc.y,vc.z,vc.w, vd.x,vd.y,vd.z,vd.w};
      float pi[16];
      float gwp = 0.f;
      #pragma unroll
      for (int k = 0; k < 16; k++) {
        pi[k] = ut*Kt[k]*vr[k];
        gwp += (-0.05f*__logf(Kt[k]))*pi[k];
      }
      size_t ob = ((size_t)bh*NN + t)*128 + m*16;
      {
        uint4 w0, w1;
        w0.x = (unsigned)f2bf(pi[0])  | ((unsigned)f2bf(pi[1])  << 16);
        w0.y = (unsigned)f2bf(pi[2])  | ((unsigned)f2bf(pi[3])  << 16);
        w0.z = (unsigned)f2bf(pi[4])  | ((unsigned)f2bf(pi[5])  << 16);
        w0.w = (unsigned)f2bf(pi[6])  | ((unsigned)f2bf(pi[7])  << 16);
        w1.x = (unsigned)f2bf(pi[8])  | ((unsigned)f2bf(pi[9])  << 16);
        w1.y = (unsigned)f2bf(pi[10]) | ((unsigned)f2bf(pi[11]) << 16);
        w1.z = (unsigned)f2bf(pi[12]) | ((unsigned)f2bf(pi[13]) << 16);
        w1.w = (unsigned)f2bf(pi[14]) | ((unsigned)f2bf(pi[15]) << 16);
        *(uint4*)(Pis + ob) = w0;
        *(uint4*)(Pis + ob + 8) = w1;
      }
      float pig[16];
      #pragma unroll
      for (int l = 0; l < 16; l++) {
        float s = 0.f;
        #pragma unroll
        for (int k = 0; k < 16; k++) s += pi[k]*Gsm[k][l];
        pig[l] = s;
      }
      {
        uint4 w0, w1;
        w0.x = (unsigned)f2bf(pig[0])  | ((unsigned)f2bf(pig[1])  << 16);
        w0.y = (unsigned)f2bf(pig[2])  | ((unsigned)f2bf(pig[3])  << 16);
        w0.z = (unsigned)f2bf(pig[4])  | ((unsigned)f2bf(pig[5])  << 16);
        w0.w = (unsigned)f2bf(pig[6])  | ((unsigned)f2bf(pig[7])  << 16);
        w1.x = (unsigned)f2bf(pig[8])  | ((unsigned)f2bf(pig[9])  << 16);
        w1.y = (unsigned)f2bf(pig[10]) | ((unsigned)f2bf(pig[11]) << 16);
        w1.z = (unsigned)f2bf(pig[12]) | ((unsigned)f2bf(pig[13]) << 16);
        w1.w = (unsigned)f2bf(pig[14]) | ((unsigned)f2bf(pig[15]) << 16);
        *(uint4*)(PiGs + ob) = w0;
        *(uint4*)(PiGs + ob + 8) = w1;
      }
      #pragma unroll
      for (int off = 1; off < 64; off <<= 1) gwp += __shfl_xor(gwp, off);
      if (lane == 0) sred[w][0] = gwp;
      __syncthreads();
      if (t == 0) {
        float S = 0.f;
        #pragma unroll
        for (int w2 = 0; w2 < 8; w2++) S += sred[w2][0];
        gwv[bh*8 + m] = S;
      }
    }
  }
}

// ---------------- alpha ----------------
__global__ void k_alpha(const float* __restrict__ gw, float* __restrict__ alpha) {
  int t = threadIdx.x;
  float gg = gw[t];
  float sc = expf(-(gg*gg));
  float s = sc;
  s += __shfl_xor(s, 1); s += __shfl_xor(s, 2); s += __shfl_xor(s, 4);
  alpha[t] = sc / fmaxf(s, 1e-8f);
}

// ---------------- Q GEMM (MFMA bf16) + alpha-fold + fused normalize + log ----------------
__global__ __launch_bounds__(256) void k_qgemm(const unsigned short* __restrict__ PiGs,
                       const unsigned short* __restrict__ Pis, const float* __restrict__ alpha,
                       float* __restrict__ out) {
  int bid = blockIdx.x;
  int blk = (bid & 7)*128 + (bid >> 3);
  int strip = blk & 15, bh = blk >> 4;
  int i0 = strip*32;
  __shared__ unsigned short As[32*128];   // 8 KB, XOR-swizzled rows
  __shared__ unsigned short Bs[128*128];  // 32 KB, XOR-swizzled rows
  __shared__ float rsum[4][32];
  __shared__ float als[8];
  int t = threadIdx.x;
  int w = t >> 6, lane = t & 63;
  if (t < 8) als[t] = alpha[bh*8 + t];
  __syncthreads();
  const unsigned short* Ab = PiGs + ((size_t)bh*NN + i0)*128;
  #pragma unroll
  for (int q = 0; q < 2; q++) {
    int idx = q*256 + t;
    int r = idx >> 4, sg = idx & 15;
    float4 v = *(const float4*)(Ab + r*128 + sg*8);
    u16x8 hv = *(u16x8*)&v;
    float a = als[sg >> 1];
    u16x8 o;
    #pragma unroll
    for (int e = 0; e < 8; e++) o[e] = f2bf(bf2f(hv[e])*a);
    *(u16x8*)&As[r*128 + (sg ^ (r & 7))*8] = o;
  }
  f32x4 acc[4][2][2] = {};
  const unsigned short* Bb = Pis + (size_t)bh*NN*128;
  for (int c = 0; c < 4; c++) {
    __syncthreads();
    #pragma unroll
    for (int q = 0; q < 8; q++) {
      int idx = q*256 + t;
      int r = idx >> 4, sg = idx & 15;
      float4 v = *(const float4*)(Bb + (size_t)(c*128 + r)*128 + sg*8);
      *(float4*)&Bs[r*128 + (sg ^ (r & 7))*8] = v;
    }
    __syncthreads();
    int col0 = w*32;
    #pragma unroll
    for (int ks = 0; ks < 4; ks++) {
      int slot = (ks*4 + (lane >> 4)) ^ (lane & 7);
      int la = lane & 15;
      bf16x8 a0 = *(bf16x8*)&As[la*128 + slot*8];
      bf16x8 a1 = *(bf16x8*)&As[(la+16)*128 + slot*8];
      bf16x8 b0 = *(bf16x8*)&Bs[(col0+la)*128 + slot*8];
      bf16x8 b1 = *(bf16x8*)&Bs[(col0+la+16)*128 + slot*8];
      acc[c][0][0] = __builtin_amdgcn_mfma_f32_16x16x32_bf16(a0, b0, acc[c][0][0], 0, 0, 0);
      acc[c][1][0] = __builtin_amdgcn_mfma_f32_16x16x32_bf16(a1, b0, acc[c][1][0], 0, 0, 0);
      acc[c][0][1] = __builtin_amdgcn_mfma_f32_16x16x32_bf16(a0, b1, acc[c][0][1], 0, 0, 0);
      acc[c][1][1] = __builtin_amdgcn_mfma_f32_16x16x32_bf16(a1, b1, acc[c][1][1], 0, 0, 0);
    }
  }
  float part[2][4];
  #pragma unroll
  for (int mt = 0; mt < 2; mt++) {
    #pragma unroll
    for (int rg = 0; rg < 4; rg++) {
      float s = 0.f;
      #pragma unroll
      for (int c = 0; c < 4; c++) {
        #pragma unroll
        for (int nt = 0; nt < 2; nt++) s += fmaxf(acc[c][mt][nt][rg], 1e-8f);
      }
      s += __shfl_xor(s, 1); s += __shfl_xor(s, 2);
      s += __shfl_xor(s, 4); s += __shfl_xor(s, 8);
      part[mt][rg] = s;
    }
  }
  if ((lane & 15) == 0) {
    int rgrp = lane >> 4;
    #pragma unroll
    for (int mt = 0; mt < 2; mt++)
      #pragma unroll
      for (int rg = 0; rg < 4; rg++)
        rsum[w][mt*16 + rgrp*4 + rg] = part[mt][rg];
  }
  __syncthreads();
  float invr[2][4];
  #pragma unroll
  for (int mt = 0; mt < 2; mt++) {
    #pragma unroll
    for (int rg = 0; rg < 4; rg++) {
      int row = mt*16 + (lane >> 4)*4 + rg;
      invr[mt][rg] = 1.f / (rsum[0][row] + rsum[1][row] + rsum[2][row] + rsum[3][row]);
    }
  }
  float* Qb = out + (size_t)QOFF + ((size_t)bh*NN + i0)*NN;
  float* Lb = out + ((size_t)bh*NN + i0)*NN;
  #pragma unroll
  for (int c = 0; c < 4; c++) {
    #pragma unroll
    for (int mt = 0; mt < 2; mt++) {
      #pragma unroll
      for (int nt = 0; nt < 2; nt++) {
        #pragma unroll
        for (int rg = 0; rg < 4; rg++) {
          int row = mt*16 + (lane >> 4)*4 + rg;
          int col = c*128 + w*32 + nt*16 + (lane & 15);
          float v = fmaxf(acc[c][mt][nt][rg], 1e-8f)*invr[mt][rg];
          Qb[(size_t)row*NN + col] = v;
          Lb[(size_t)row*NN + col] = __logf(v);
        }
      }
    }
  }
}

// ---------------- slot usage ----------------
__global__ __launch_bounds__(256) void k_usage(const float* __restrict__ z, const float* __restrict__ Wp,
                        const float* __restrict__ bp, float* __restrict__ partial) {
  __shared__ float wps[256][9];
  __shared__ float red[256][8];
  int t = threadIdx.x;
  {
    float4 a = *(const float4*)(Wp + t*8);
    float4 b = *(const float4*)(Wp + t*8 + 4);
    wps[t][0]=a.x; wps[t][1]=a.y; wps[t][2]=a.z; wps[t][3]=a.w;
    wps[t][4]=b.x; wps[t][5]=b.y; wps[t][6]=b.z; wps[t][7]=b.w;
  }
  __syncthreads();
  int row = blockIdx.x*256 + t;
  const float* zr = z + (size_t)row*ND;
  float acc[8] = {};
  for (int d0 = 0; d0 < ND; d0 += 4) {
    float4 v = *(const float4*)(zr + d0);
    #pragma unroll
    for (int m = 0; m < 8; m++) {
      acc[m] += v.x*wps[d0][m] + v.y*wps[d0+1][m] + v.z*wps[d0+2][m] + v.w*wps[d0+3][m];
    }
  }
  float mx = -1e30f;
  #pragma unroll
  for (int m = 0; m < 8; m++) { acc[m] += bp[m]; mx = fmaxf(mx, acc[m]); }
  float s = 0.f;
  #pragma unroll
  for (int m = 0; m < 8; m++) { acc[m] = expf(acc[m]-mx); s += acc[m]; }
  float inv = 1.f/s;
  #pragma unroll
  for (int m = 0; m < 8; m++) red[t][m] = acc[m]*inv;
  __syncthreads();
  for (int q = 128; q > 0; q >>= 1) {
    if (t < q) { for (int m = 0; m < 8; m++) red[t][m] += red[t+q][m]; }
    __syncthreads();
  }
  if (t < 8) partial[blockIdx.x*8 + t] = red[0][t];
}

// ---------------- final scalar ----------------
__global__ void k_final(const float* __restrict__ greg, const float* __restrict__ partial,
                        float* __restrict__ out) {
  if (threadIdx.x == 0) {
    float us[8] = {};
    for (int b = 0; b < 16; b++)
      for (int m = 0; m < 8; m++) us[m] += partial[b*8 + m];
    float kl = 0.f;
    for (int m = 0; m < 8; m++) {
      float u = us[m] / (float)BN;
      kl += u*logf(fmaxf(u, 1e-8f)*(float)NM);
    }
    out[33554432] = greg[0] + 0.01f*kl;
  }
}

extern "C" void kernel_launch(void* const* d_in, const int* in_sizes, int n_in,
                              void* d_out, int out_size, void* d_ws, size_t ws_size,
                              hipStream_t stream) {
  const float* xd = (const float*)d_in[0];
  const float* xn = (const float*)d_in[1];
  const float* W1 = (const float*)d_in[2];
  const float* b1 = (const float*)d_in[3];
  const float* W2 = (const float*)d_in[4];
  const float* b2 = (const float*)d_in[5];
  const float* Wp = (const float*)d_in[6];
  const float* bp = (const float*)d_in[7];
  const float* Up = (const float*)d_in[8];
  float* out = (float*)d_out;
  float* ws  = (float*)d_ws;

  float* z   = ws + 0;                                    // 1,048,576 f
  float* hid = ws + 1048576;                              // 1,048,576 f
  float* zh  = ws + 2097152;                              // 1,048,576 f
  unsigned short* PiGs = (unsigned short*)(ws + 3145728); // 4,194,304 u16
  unsigned short* Pis  = (unsigned short*)(ws + 5242880); // 4,194,304 u16
  float* gw    = ws + 7340032;
  float* alpha = ws + 7340544;
  float* G     = ws + 7341056;
  float* DG    = ws + 7343104;
  float* greg  = ws + 7345152;
  float* partial = ws + 7345153;
  float* rsb   = ws + 7345664;    // 32768 f
  float* rqb   = ws + 7378432;    // 32768 f

  // d_out doubles as scratch:
  //  - bias region: P (bf16, 33.5 MB) until k_dp; then qgemm writes bias_log
  //  - Q region: DPt (bf16) + DQt (bf16) fragment-major = 67 MB; qgemm overwrites with Q
  unsigned short* P16 = (unsigned short*)out;
  unsigned short* DPt = (unsigned short*)(out + QOFF);
  unsigned short* DQt = DPt + (size_t)16777216;

  k_mlp1<<<dim3(4, 64), 256, 0, stream>>>(xd, xn, W1, b1, hid);
  k_mlp2<<<dim3(4, 64), 256, 0, stream>>>(hid, W2, b2, z);
  k_usage<<<16, 256, 0, stream>>>(z, Wp, bp, partial);
  k_zhnorm<<<4096, 256, 0, stream>>>(z, zh);
  k_affinity<<<1024, 256, 0, stream>>>(zh, P16);
  k_dp<<<1024, 256, 0, stream>>>(P16, DPt, DQt, rsb, rqb);
  k_slots<<<1, 256, 0, stream>>>(Up, G, DG, greg);
  k_gw<<<512, 512, 0, stream>>>(DPt, DQt, rsb, rqb, G, DG, PiGs, Pis, gw);
  k_alpha<<<1, 512, 0, stream>>>(gw, alpha);
  k_qgemm<<<1024, 256, 0, stream>>>(PiGs, Pis, alpha, out);
  k_final<<<1, 64, 0, stream>>>(greg, partial, out);
}